// Round 5
// baseline (199.374 us; speedup 1.0000x reference)
//
#include <hip/hip_runtime.h>

typedef unsigned short u16;
typedef __attribute__((ext_vector_type(8))) __bf16 bf16x8;
typedef __attribute__((ext_vector_type(4))) float f32x4;
typedef __attribute__((ext_vector_type(16))) float f32x16;

#define LOG2E 1.44269504088896f

__device__ __forceinline__ u16 f2bf(float f) {
  union { float f; unsigned u; } c; c.f = f;
  unsigned u = c.u;
  return (u16)((u + 0x7fffu + ((u >> 16) & 1u)) >> 16);
}

__device__ __forceinline__ void load_lds16(const void* g, void* l) {
  __builtin_amdgcn_global_load_lds((const __attribute__((address_space(1))) unsigned int*)g,
                                   (__attribute__((address_space(3))) unsigned int*)l, 16, 0, 0);
}

// ---------------- cast f32 -> bf16 (x and enc fused) ----------------
__global__ void cast2_kernel(const float* __restrict__ a, const float* __restrict__ b,
                             u16* __restrict__ oa, u16* __restrict__ ob, int n4each) {
  int stride = gridDim.x * blockDim.x;
  for (int i = blockIdx.x * blockDim.x + threadIdx.x; i < 2 * n4each; i += stride) {
    const float4* src; ushort4* dst; int j;
    if (i < n4each) { src = (const float4*)a; dst = (ushort4*)oa; j = i; }
    else            { src = (const float4*)b; dst = (ushort4*)ob; j = i - n4each; }
    float4 v = src[j];
    ushort4 o;
    o.x = f2bf(v.x); o.y = f2bf(v.y); o.z = f2bf(v.z); o.w = f2bf(v.w);
    dst[j] = o;
  }
}

// ---------------- transpose + cast all 4 weights ----------------
__global__ void transpose_cast4_kernel(const float* __restrict__ Wq, const float* __restrict__ Wk,
                                       const float* __restrict__ Wv, const float* __restrict__ Wo,
                                       u16* __restrict__ WqT, u16* __restrict__ WkT,
                                       u16* __restrict__ WvT, u16* __restrict__ WoT) {
  __shared__ float tile[32][33];
  const float* in; u16* out; int C;
  int z = blockIdx.z;
  if (z == 0)      { in = Wq; out = WqT; C = 1024; }
  else if (z == 1) { in = Wk; out = WkT; C = 512; }
  else if (z == 2) { in = Wv; out = WvT; C = 512; }
  else             { in = Wo; out = WoT; C = 1024; }
  const int R = 1024;
  int c0 = blockIdx.x * 32, r0 = blockIdx.y * 32;
  if (c0 >= C) return;
  int tx = threadIdx.x, ty = threadIdx.y; // (32,8)
#pragma unroll
  for (int i = 0; i < 4; ++i)
    tile[ty + 8 * i][tx] = in[(size_t)(r0 + ty + 8 * i) * C + c0 + tx];
  __syncthreads();
#pragma unroll
  for (int i = 0; i < 4; ++i)
    out[(size_t)(c0 + ty + 8 * i) * R + r0 + tx] = f2bf(tile[tx][ty + 8 * i]);
}

// ---------------- 128x128 bf16 B^T GEMM body (BK=64, swizzled LDS) ----------------
__device__ __forceinline__ void gemm128_body(const u16* A, const u16* Bt, float* C,
                                             int N, int K, u16* As, u16* Bs) {
  int tid = threadIdx.x;
  int w = tid >> 6, l = tid & 63;
  int g = l >> 4, lr = l & 15;
  int m0 = blockIdx.x * 128, n0 = blockIdx.y * 128;
  int wr = w >> 1, wc = w & 1;
  f32x4 acc[4][4];
#pragma unroll
  for (int m = 0; m < 4; ++m)
#pragma unroll
    for (int n = 0; n < 4; ++n) acc[m][n] = (f32x4){0.f, 0.f, 0.f, 0.f};

  for (int k0 = 0; k0 < K; k0 += 64) {
#pragma unroll
    for (int rnd = 0; rnd < 4; ++rnd) {
      int bidx = rnd * 4096 + w * 1024 + l * 16;
      int row = bidx >> 7, colb = bidx & 127;
      int scol = colb ^ ((row & 7) << 4);
      load_lds16((const char*)A + ((size_t)(m0 + row) * K + k0) * 2 + scol,
                 (char*)As + rnd * 4096 + w * 1024);
      load_lds16((const char*)Bt + ((size_t)(n0 + row) * K + k0) * 2 + scol,
                 (char*)Bs + rnd * 4096 + w * 1024);
    }
    __syncthreads();
    bf16x8 af[4][2], bfr[4][2];
#pragma unroll
    for (int m = 0; m < 4; ++m) {
      int ra = wr * 64 + m * 16 + lr;
      int rb = wc * 64 + m * 16 + lr;
#pragma unroll
      for (int kf = 0; kf < 2; ++kf) {
        af[m][kf]  = *(const bf16x8*)((const char*)As + ra * 128 + ((kf * 64 + g * 16) ^ ((ra & 7) << 4)));
        bfr[m][kf] = *(const bf16x8*)((const char*)Bs + rb * 128 + ((kf * 64 + g * 16) ^ ((rb & 7) << 4)));
      }
    }
#pragma unroll
    for (int m = 0; m < 4; ++m)
#pragma unroll
      for (int n = 0; n < 4; ++n) {
        acc[m][n] = __builtin_amdgcn_mfma_f32_16x16x32_bf16(af[m][0], bfr[n][0], acc[m][n], 0, 0, 0);
        acc[m][n] = __builtin_amdgcn_mfma_f32_16x16x32_bf16(af[m][1], bfr[n][1], acc[m][n], 0, 0, 0);
      }
    __syncthreads();
  }
#pragma unroll
  for (int m = 0; m < 4; ++m)
#pragma unroll
    for (int n = 0; n < 4; ++n) {
      int row = m0 + wr * 64 + m * 16 + g * 4;
      int col = n0 + wc * 64 + n * 16 + lr;
#pragma unroll
      for (int r = 0; r < 4; ++r)
        C[(size_t)(row + r) * N + col] = acc[m][n][r];
    }
}

__global__ __launch_bounds__(256, 2) void gemm_qkv_kernel(const u16* xb, const u16* eb,
                                                          const u16* WqT, const u16* WkT, const u16* WvT,
                                                          float* qr, float* kr, float* vr) {
  __shared__ __align__(16) u16 As[128 * 64];
  __shared__ __align__(16) u16 Bs[128 * 64];
  int z = blockIdx.z;
  const u16* A; const u16* Bt; float* C; int N;
  if (z == 0)      { A = xb; Bt = WqT; C = qr; N = 1024; }
  else if (z == 1) { A = eb; Bt = WkT; C = kr; N = 512; }
  else             { A = eb; Bt = WvT; C = vr; N = 512; }
  if ((int)blockIdx.y * 128 >= N) return;
  gemm128_body(A, Bt, C, N, 1024, As, Bs);
}

__global__ __launch_bounds__(256, 2) void gemm_out_kernel(const u16* Yb, const u16* WoT, float* out) {
  __shared__ __align__(16) u16 As[128 * 64];
  __shared__ __align__(16) u16 Bs[128 * 64];
  gemm128_body(Yb, WoT, out, 1024, 1024, As, Bs);
}

// ---------------- Q+K epilogue (fused): l2norm + scale + rope + store (B,heads,T,64) bf16 ----------------
__global__ void epilogue_qk2_kernel(const float* __restrict__ qr, const float* __restrict__ kr,
                                    const float* __restrict__ qscale, const float* __restrict__ kscale,
                                    const float* __restrict__ freqs,
                                    u16* __restrict__ Qb, u16* __restrict__ Kb) {
  int unit = blockIdx.x * 4 + (threadIdx.x >> 6);
  int lane = threadIdx.x & 63;
  const float* raw; const float* scale; u16* out; int hshift; float final_scale;
  // Q carries all score scaling incl. LOG2E so softmax uses exp2 directly.
  if (unit < 65536) { raw = qr; scale = qscale; out = Qb; hshift = 4; final_scale = 0.0015625f * LOG2E; }
  else { unit -= 65536; raw = kr; scale = kscale; out = Kb; hshift = 3; final_scale = 1.0f; }
  int nheads = 1 << hshift;
  int hd = unit & (nheads - 1);
  int row = unit >> hshift;        // b*1024 + t
  int t = row & 1023;
  int b = row >> 10;
  float v = raw[(size_t)row * (nheads * 64) + hd * 64 + lane];
  float ss = v * v;
#pragma unroll
  for (int d = 1; d < 64; d <<= 1) ss += __shfl_xor(ss, d);
  float inv = 1.0f / fmaxf(sqrtf(ss), 1e-12f);
  v = v * inv * scale[lane];
  float f = (lane < 32) ? freqs[t * 32 + lane] : 0.0f;
  float sn, cs;
  sincosf(f, &sn, &cs);
  float partner = __shfl_xor(v, 1);
  float rot = (lane & 1) ? partner : -partner;
  float vrot = v * cs + rot * sn;
  if (lane < 32) v = vrot;
  v *= final_scale;
  out[(((size_t)b * nheads + hd) * 1024 + t) * 64 + lane] = f2bf(v);
}

// ---------------- V epilogue: rope + store transposed (B,KV,D,T) bf16 ----------------
__global__ void epilogue_v_kernel(const float* __restrict__ v_raw, const float* __restrict__ freqs,
                                  u16* __restrict__ Vt) {
  __shared__ __align__(16) u16 tile[64][72];
  int blk = blockIdx.x;
  int t0 = (blk & 15) * 64;
  int kvg = blk >> 4;            // b*8 + kv
  int kvv = kvg & 7;
  int bb = kvg >> 3;
  int tid = threadIdx.x;
  int tl = tid >> 2;             // token local 0..63
  int dq = (tid & 3) * 16;       // dim base
  int t = t0 + tl;
  const float* src = v_raw + ((size_t)(bb * 1024 + t)) * 512 + kvv * 64 + dq;
  float x[16];
#pragma unroll
  for (int i = 0; i < 4; ++i) {
    float4 q = *(const float4*)(src + i * 4);
    x[i * 4 + 0] = q.x; x[i * 4 + 1] = q.y; x[i * 4 + 2] = q.z; x[i * 4 + 3] = q.w;
  }
  if (dq < 32) {
#pragma unroll
    for (int j = 0; j < 8; ++j) {
      int d = dq + 2 * j;
      float f = freqs[t * 32 + d];
      float sn, cs; sincosf(f, &sn, &cs);
      float e = x[2 * j], o = x[2 * j + 1];
      x[2 * j]     = e * cs - o * sn;
      x[2 * j + 1] = o * cs + e * sn;
    }
  }
#pragma unroll
  for (int i = 0; i < 16; ++i) tile[dq + i][tl] = f2bf(x[i]);
  __syncthreads();
#pragma unroll
  for (int rnd = 0; rnd < 2; ++rnd) {
    int chunk = rnd * 256 + tid;
    int drow = chunk >> 3, c8 = chunk & 7;
    bf16x8 val = *(const bf16x8*)((const char*)&tile[0][0] + drow * 144 + c8 * 16);
    *(bf16x8*)(Vt + ((size_t)kvg * 64 + drow) * 1024 + t0 + c8 * 8) = val;
  }
}

// ---------------- flash attention: 4-wave intra-block split-K, swapped 32x32 MFMA ----------------
// Wave w handles 32-key steps {w, w+4, w+8, ...}; barrier-free K-loop; LDS merge at end.
// S^T = K·Q^T -> lane (q=lane&31, hi=lane>>5) holds S[key=crow(r,hi)][q], crow=(r&3)+8*(r>>2)+4*hi
// O^T = V^T·P^T -> same lane holds O[d=32*dh+crow(r,hi)][q]
__device__ __forceinline__ unsigned pack_bf2(float lo, float hi_) {
  union { __bf16 h[2]; unsigned u; } c;
  c.h[0] = (__bf16)lo; c.h[1] = (__bf16)hi_;
  return c.u;
}

__global__ __launch_bounds__(256, 4) void attn_kernel(const u16* __restrict__ Qb, const u16* __restrict__ Kb,
                                                      const u16* __restrict__ Vtb, const float* __restrict__ bias,
                                                      u16* __restrict__ Yb) {
  __shared__ __align__(16) float Osh[4][64][32];   // 32 KB f32 partial O^T per wave
  __shared__ float Msh[4][32];
  __shared__ float Lsh[4][32];
  int tid = threadIdx.x;
  int w = tid >> 6;              // wave index = key-split slot
  int lane = tid & 63;
  int ql = lane & 31;            // this lane's query column
  int hi = lane >> 5;
  int x = blockIdx.x;
  int qt = 31 - (x >> 6);        // qt descending: long blocks dispatch first
  int bh = x & 63;               // h*4 + b : b fastest => 4 batches share bias panel in L2
  int b = bh & 3, h = bh >> 2, kv = h & 7;
  int qg = qt * 32 + ql;         // global query row
  int nt = qt + 1;               // total 32-key steps (causal)

  // Q fragments (B-operand): col=ql, per-lane 8 dims at hi*8 within each 16-dim k-slice
  const u16* Qrow = Qb + ((size_t)(b * 16 + h) * 1024 + qg) * 64;
  bf16x8 qf[4];
#pragma unroll
  for (int ks = 0; ks < 4; ++ks) qf[ks] = *(const bf16x8*)(Qrow + ks * 16 + hi * 8);

  const u16* Kfp = Kb + (size_t)(b * 8 + kv) * 1024 * 64 + (size_t)ql * 64 + hi * 8;
  const u16* Vfp = Vtb + (size_t)(b * 8 + kv) * 64 * 1024 + (size_t)ql * 1024 + hi * 8;
  const float* biasrow = bias + (size_t)h * 1024 * 1024 + (size_t)qg * 1024;

  f32x16 o0, o1;
#pragma unroll
  for (int r = 0; r < 16; ++r) { o0[r] = 0.f; o1[r] = 0.f; }
  float m = -1e30f, lsum = 0.f;

  // prologue: this wave's first step (w*32) K + bias (always in-bounds; unused if w >= nt)
  bf16x8 kc[4];
  float bcf[16];
  {
    int t0 = w * 32;
#pragma unroll
    for (int ks = 0; ks < 4; ++ks) kc[ks] = *(const bf16x8*)(Kfp + (size_t)t0 * 64 + ks * 16);
#pragma unroll
    for (int c = 0; c < 4; ++c) {
      float4 t = *(const float4*)(biasrow + t0 + 8 * c + 4 * hi);
      bcf[c * 4 + 0] = t.x; bcf[c * 4 + 1] = t.y; bcf[c * 4 + 2] = t.z; bcf[c * 4 + 3] = t.w;
    }
  }

  for (int it = w; it < nt; it += 4) {
    int t0 = it * 32;
    bool hn = (it + 4) < nt;
    // prefetch this wave's next step (t0+128): hides L2 latency under this step's compute
    bf16x8 kn[4];
    float bnf[16];
    if (hn) {
#pragma unroll
      for (int ks = 0; ks < 4; ++ks) kn[ks] = *(const bf16x8*)(Kfp + (size_t)(t0 + 128) * 64 + ks * 16);
#pragma unroll
      for (int c = 0; c < 4; ++c) {
        float4 t = *(const float4*)(biasrow + t0 + 128 + 8 * c + 4 * hi);
        bnf[c * 4 + 0] = t.x; bnf[c * 4 + 1] = t.y; bnf[c * 4 + 2] = t.z; bnf[c * 4 + 3] = t.w;
      }
    }
    // ---- S^T = K · Q^T (scales + log2e folded into Q; bias folded at epilogue below) ----
    f32x16 s;
#pragma unroll
    for (int r = 0; r < 16; ++r) s[r] = 0.f;
#pragma unroll
    for (int ks = 0; ks < 4; ++ks)
      s = __builtin_amdgcn_mfma_f32_32x32x16_bf16(kc[ks], qf[ks], s, 0, 0, 0);
    // V fragments for this step (A-operand of O^T)
    bf16x8 vf[2][2];
#pragma unroll
    for (int dh = 0; dh < 2; ++dh)
#pragma unroll
      for (int k2 = 0; k2 < 2; ++k2)
        vf[dh][k2] = *(const bf16x8*)(Vfp + (size_t)dh * 32 * 1024 + t0 + k2 * 16);
    // ---- bias + causal mask ----
    bool diag = (it == nt - 1);
    float p[16];
#pragma unroll
    for (int r = 0; r < 16; ++r) {
      int key = t0 + (r & 3) + 8 * (r >> 2) + 4 * hi;
      float sv = s[r] + bcf[r];
      if (diag && key > qg) sv = -1e30f;
      p[r] = sv;
    }
    // ---- row max: in-register tree + one xor-32 exchange ----
    float t8[8];
#pragma unroll
    for (int j = 0; j < 8; ++j) t8[j] = fmaxf(p[2 * j], p[2 * j + 1]);
    float t4a = fmaxf(t8[0], t8[1]), t4b = fmaxf(t8[2], t8[3]);
    float t4c = fmaxf(t8[4], t8[5]), t4d = fmaxf(t8[6], t8[7]);
    float mx = fmaxf(fmaxf(t4a, t4b), fmaxf(t4c, t4d));
    mx = fmaxf(mx, __shfl_xor(mx, 32));
    // ---- defer-max (THR=8 in log2 units): rescale only when some row grew past m+8 ----
    if (!__all(mx <= m + 8.0f)) {
      float mn = fmaxf(m, mx);
      float sf = exp2f(m - mn);
      m = mn;
      lsum *= sf;
#pragma unroll
      for (int r = 0; r < 16; ++r) { o0[r] *= sf; o1[r] *= sf; }
    }
    // ---- exponentiate (bounded by 2^8) + lane-partial sum ----
    float ssum = 0.f;
#pragma unroll
    for (int r = 0; r < 16; ++r) {
      p[r] = exp2f(p[r] - m);
      ssum += p[r];
    }
    lsum += ssum;
    // ---- pack P -> bf16 pairs, redistribute across the hi-split (8 xor-32 shuffles) ----
    unsigned pk[8], tk[8];
#pragma unroll
    for (int j = 0; j < 8; ++j) pk[j] = pack_bf2(p[2 * j], p[2 * j + 1]);
#pragma unroll
    for (int j = 0; j < 8; ++j) tk[j] = (unsigned)__shfl_xor((int)pk[j], 32);
    union PU { unsigned u[4]; bf16x8 v; };
    PU pb0, pb1;
    pb0.u[0] = hi ? tk[2] : pk[0];
    pb0.u[1] = hi ? tk[3] : pk[1];
    pb0.u[2] = hi ? pk[2] : tk[0];
    pb0.u[3] = hi ? pk[3] : tk[1];
    pb1.u[0] = hi ? tk[6] : pk[4];
    pb1.u[1] = hi ? tk[7] : pk[5];
    pb1.u[2] = hi ? pk[6] : tk[4];
    pb1.u[3] = hi ? pk[7] : tk[5];
    // ---- O^T += V^T · P^T ----
    o0 = __builtin_amdgcn_mfma_f32_32x32x16_bf16(vf[0][0], pb0.v, o0, 0, 0, 0);
    o0 = __builtin_amdgcn_mfma_f32_32x32x16_bf16(vf[0][1], pb1.v, o0, 0, 0, 0);
    o1 = __builtin_amdgcn_mfma_f32_32x32x16_bf16(vf[1][0], pb0.v, o1, 0, 0, 0);
    o1 = __builtin_amdgcn_mfma_f32_32x32x16_bf16(vf[1][1], pb1.v, o1, 0, 0, 0);
    // roll prefetch
    if (hn) {
#pragma unroll
      for (int ks = 0; ks < 4; ++ks) kc[ks] = kn[ks];
#pragma unroll
      for (int r = 0; r < 16; ++r) bcf[r] = bnf[r];
    }
  }

  // ---- write this wave's partial state to LDS ----
  lsum += __shfl_xor(lsum, 32);
#pragma unroll
  for (int r = 0; r < 16; ++r) {
    int row = (r & 3) + 8 * (r >> 2) + 4 * hi;
    Osh[w][row][ql]      = o0[r];
    Osh[w][row + 32][ql] = o1[r];
  }
  if (hi == 0) { Msh[w][ql] = m; Lsh[w][ql] = lsum; }
  __syncthreads();

  // ---- merge 4 partials: thread handles (q = tid&31, d = (tid>>5)*8 .. +7) ----
  {
    int q = tid & 31, dg = tid >> 5;
    float m0 = Msh[0][q], m1 = Msh[1][q], m2 = Msh[2][q], m3 = Msh[3][q];
    float mM = fmaxf(fmaxf(m0, m1), fmaxf(m2, m3));
    float w0 = exp2f(m0 - mM), w1 = exp2f(m1 - mM);
    float w2 = exp2f(m2 - mM), w3 = exp2f(m3 - mM);
    float ltot = w0 * Lsh[0][q] + w1 * Lsh[1][q] + w2 * Lsh[2][q] + w3 * Lsh[3][q];
    float invl = 1.0f / ltot;
    ushort4 out0, out1;
    u16 ov[8];
#pragma unroll
    for (int j = 0; j < 8; ++j) {
      int d = dg * 8 + j;
      float acc = w0 * Osh[0][d][q] + w1 * Osh[1][d][q] + w2 * Osh[2][d][q] + w3 * Osh[3][d][q];
      ov[j] = f2bf(acc * invl);
    }
    out0.x = ov[0]; out0.y = ov[1]; out0.z = ov[2]; out0.w = ov[3];
    out1.x = ov[4]; out1.y = ov[5]; out1.z = ov[6]; out1.w = ov[7];
    u16* Yp = Yb + ((size_t)b * 1024 + qt * 32 + q) * 1024 + h * 64 + dg * 8;
    *(ushort4*)Yp = out0;
    *(ushort4*)(Yp + 4) = out1;
  }
}

extern "C" void kernel_launch(void* const* d_in, const int* in_sizes, int n_in,
                              void* d_out, int out_size, void* d_ws, size_t ws_size,
                              hipStream_t stream) {
  const float* x     = (const float*)d_in[0];
  const float* enc   = (const float*)d_in[1];
  const float* freqs = (const float*)d_in[2];
  const float* bias  = (const float*)d_in[3];
  const float* Wq    = (const float*)d_in[4];
  const float* Wk    = (const float*)d_in[5];
  const float* Wv    = (const float*)d_in[6];
  const float* Wo    = (const float*)d_in[7];
  const float* qs    = (const float*)d_in[8];
  const float* ks    = (const float*)d_in[9];

  char* ws = (char*)d_ws;
  size_t off = 0;
  auto alloc = [&](size_t bytes) { char* p = ws + off; off += (bytes + 255) & ~(size_t)255; return p; };
  u16*   xb  = (u16*)alloc(8388608);    // x bf16 (4096 x 1024)
  u16*   eb  = (u16*)alloc(8388608);    // enc bf16
  u16*   WqT = (u16*)alloc(2097152);    // (1024 x 1024)
  u16*   WkT = (u16*)alloc(1048576);    // (512 x 1024)
  u16*   WvT = (u16*)alloc(1048576);
  u16*   WoT = (u16*)alloc(2097152);
  float* qr  = (float*)alloc(16777216); // q raw f32 (4096 x 1024)
  float* kr  = (float*)alloc(8388608);  // k raw (4096 x 512)
  float* vr  = (float*)alloc(8388608);
  u16*   Qb  = (u16*)alloc(8388608);    // (B,H,T,D) bf16
  u16*   Kbb = (u16*)alloc(4194304);    // (B,KV,T,D)
  u16*   Vtb = (u16*)alloc(4194304);    // (B,KV,D,T)
  u16*   Yb  = (u16*)xb;                // alias: xb dead after QKV GEMM

  cast2_kernel<<<2048, 256, 0, stream>>>(x, enc, xb, eb, 1048576);
  transpose_cast4_kernel<<<dim3(32, 32, 4), dim3(32, 8), 0, stream>>>(Wq, Wk, Wv, Wo, WqT, WkT, WvT, WoT);

  gemm_qkv_kernel<<<dim3(32, 8, 3), 256, 0, stream>>>(xb, eb, WqT, WkT, WvT, qr, kr, vr);

  epilogue_qk2_kernel<<<24576, 256, 0, stream>>>(qr, kr, qs, ks, freqs, Qb, Kbb);
  epilogue_v_kernel<<<512, 256, 0, stream>>>(vr, freqs, Vtb);

  attn_kernel<<<dim3(2048), 256, 0, stream>>>(Qb, Kbb, Vtb, bias, Yb);

  gemm_out_kernel<<<dim3(32, 8), 256, 0, stream>>>(Yb, WoT, (float*)d_out);
}

// Round 6
// 141.605 us; speedup vs baseline: 1.4080x; 1.4080x over previous
//
#include <hip/hip_runtime.h>

typedef unsigned short u16;
typedef __attribute__((ext_vector_type(8))) __bf16 bf16x8;
typedef __attribute__((ext_vector_type(4))) float f32x4;
typedef __attribute__((ext_vector_type(16))) float f32x16;

#define LOG2E 1.44269504088896f

__device__ __forceinline__ u16 f2bf(float f) {
  union { float f; unsigned u; } c; c.f = f;
  unsigned u = c.u;
  return (u16)((u + 0x7fffu + ((u >> 16) & 1u)) >> 16);
}

__device__ __forceinline__ void load_lds16(const void* g, void* l) {
  __builtin_amdgcn_global_load_lds((const __attribute__((address_space(1))) unsigned int*)g,
                                   (__attribute__((address_space(3))) unsigned int*)l, 16, 0, 0);
}

// ---------------- cast f32 -> bf16 (x and enc fused) ----------------
__global__ void cast2_kernel(const float* __restrict__ a, const float* __restrict__ b,
                             u16* __restrict__ oa, u16* __restrict__ ob, int n4each) {
  int stride = gridDim.x * blockDim.x;
  for (int i = blockIdx.x * blockDim.x + threadIdx.x; i < 2 * n4each; i += stride) {
    const float4* src; ushort4* dst; int j;
    if (i < n4each) { src = (const float4*)a; dst = (ushort4*)oa; j = i; }
    else            { src = (const float4*)b; dst = (ushort4*)ob; j = i - n4each; }
    float4 v = src[j];
    ushort4 o;
    o.x = f2bf(v.x); o.y = f2bf(v.y); o.z = f2bf(v.z); o.w = f2bf(v.w);
    dst[j] = o;
  }
}

// ---------------- transpose + cast all 4 weights ----------------
__global__ void transpose_cast4_kernel(const float* __restrict__ Wq, const float* __restrict__ Wk,
                                       const float* __restrict__ Wv, const float* __restrict__ Wo,
                                       u16* __restrict__ WqT, u16* __restrict__ WkT,
                                       u16* __restrict__ WvT, u16* __restrict__ WoT) {
  __shared__ float tile[32][33];
  const float* in; u16* out; int C;
  int z = blockIdx.z;
  if (z == 0)      { in = Wq; out = WqT; C = 1024; }
  else if (z == 1) { in = Wk; out = WkT; C = 512; }
  else if (z == 2) { in = Wv; out = WvT; C = 512; }
  else             { in = Wo; out = WoT; C = 1024; }
  const int R = 1024;
  int c0 = blockIdx.x * 32, r0 = blockIdx.y * 32;
  if (c0 >= C) return;
  int tx = threadIdx.x, ty = threadIdx.y; // (32,8)
#pragma unroll
  for (int i = 0; i < 4; ++i)
    tile[ty + 8 * i][tx] = in[(size_t)(r0 + ty + 8 * i) * C + c0 + tx];
  __syncthreads();
#pragma unroll
  for (int i = 0; i < 4; ++i)
    out[(size_t)(c0 + ty + 8 * i) * R + r0 + tx] = f2bf(tile[tx][ty + 8 * i]);
}

// ---------------- 128x128 bf16 B^T GEMM body (BK=64, swizzled LDS) ----------------
__device__ __forceinline__ void gemm128_body(const u16* A, const u16* Bt, float* C,
                                             int N, int K, u16* As, u16* Bs) {
  int tid = threadIdx.x;
  int w = tid >> 6, l = tid & 63;
  int g = l >> 4, lr = l & 15;
  int m0 = blockIdx.x * 128, n0 = blockIdx.y * 128;
  int wr = w >> 1, wc = w & 1;
  f32x4 acc[4][4];
#pragma unroll
  for (int m = 0; m < 4; ++m)
#pragma unroll
    for (int n = 0; n < 4; ++n) acc[m][n] = (f32x4){0.f, 0.f, 0.f, 0.f};

  for (int k0 = 0; k0 < K; k0 += 64) {
#pragma unroll
    for (int rnd = 0; rnd < 4; ++rnd) {
      int bidx = rnd * 4096 + w * 1024 + l * 16;
      int row = bidx >> 7, colb = bidx & 127;
      int scol = colb ^ ((row & 7) << 4);
      load_lds16((const char*)A + ((size_t)(m0 + row) * K + k0) * 2 + scol,
                 (char*)As + rnd * 4096 + w * 1024);
      load_lds16((const char*)Bt + ((size_t)(n0 + row) * K + k0) * 2 + scol,
                 (char*)Bs + rnd * 4096 + w * 1024);
    }
    __syncthreads();
    bf16x8 af[4][2], bfr[4][2];
#pragma unroll
    for (int m = 0; m < 4; ++m) {
      int ra = wr * 64 + m * 16 + lr;
      int rb = wc * 64 + m * 16 + lr;
#pragma unroll
      for (int kf = 0; kf < 2; ++kf) {
        af[m][kf]  = *(const bf16x8*)((const char*)As + ra * 128 + ((kf * 64 + g * 16) ^ ((ra & 7) << 4)));
        bfr[m][kf] = *(const bf16x8*)((const char*)Bs + rb * 128 + ((kf * 64 + g * 16) ^ ((rb & 7) << 4)));
      }
    }
#pragma unroll
    for (int m = 0; m < 4; ++m)
#pragma unroll
      for (int n = 0; n < 4; ++n) {
        acc[m][n] = __builtin_amdgcn_mfma_f32_16x16x32_bf16(af[m][0], bfr[n][0], acc[m][n], 0, 0, 0);
        acc[m][n] = __builtin_amdgcn_mfma_f32_16x16x32_bf16(af[m][1], bfr[n][1], acc[m][n], 0, 0, 0);
      }
    __syncthreads();
  }
#pragma unroll
  for (int m = 0; m < 4; ++m)
#pragma unroll
    for (int n = 0; n < 4; ++n) {
      int row = m0 + wr * 64 + m * 16 + g * 4;
      int col = n0 + wc * 64 + n * 16 + lr;
#pragma unroll
      for (int r = 0; r < 4; ++r)
        C[(size_t)(row + r) * N + col] = acc[m][n][r];
    }
}

__global__ __launch_bounds__(256, 2) void gemm_qkv_kernel(const u16* xb, const u16* eb,
                                                          const u16* WqT, const u16* WkT, const u16* WvT,
                                                          float* qr, float* kr, float* vr) {
  __shared__ __align__(16) u16 As[128 * 64];
  __shared__ __align__(16) u16 Bs[128 * 64];
  int z = blockIdx.z;
  const u16* A; const u16* Bt; float* C; int N;
  if (z == 0)      { A = xb; Bt = WqT; C = qr; N = 1024; }
  else if (z == 1) { A = eb; Bt = WkT; C = kr; N = 512; }
  else             { A = eb; Bt = WvT; C = vr; N = 512; }
  if ((int)blockIdx.y * 128 >= N) return;
  gemm128_body(A, Bt, C, N, 1024, As, Bs);
}

__global__ __launch_bounds__(256, 2) void gemm_out_kernel(const u16* Yb, const u16* WoT, float* out) {
  __shared__ __align__(16) u16 As[128 * 64];
  __shared__ __align__(16) u16 Bs[128 * 64];
  gemm128_body(Yb, WoT, out, 1024, 1024, As, Bs);
}

// ---------------- Q+K epilogue (fused): l2norm + scale + rope + store (B,heads,T,64) bf16 ----------------
__global__ void epilogue_qk2_kernel(const float* __restrict__ qr, const float* __restrict__ kr,
                                    const float* __restrict__ qscale, const float* __restrict__ kscale,
                                    const float* __restrict__ freqs,
                                    u16* __restrict__ Qb, u16* __restrict__ Kb) {
  int unit = blockIdx.x * 4 + (threadIdx.x >> 6);
  int lane = threadIdx.x & 63;
  const float* raw; const float* scale; u16* out; int hshift; float final_scale;
  // Q carries all score scaling incl. LOG2E so softmax uses exp2 directly.
  if (unit < 65536) { raw = qr; scale = qscale; out = Qb; hshift = 4; final_scale = 0.0015625f * LOG2E; }
  else { unit -= 65536; raw = kr; scale = kscale; out = Kb; hshift = 3; final_scale = 1.0f; }
  int nheads = 1 << hshift;
  int hd = unit & (nheads - 1);
  int row = unit >> hshift;        // b*1024 + t
  int t = row & 1023;
  int b = row >> 10;
  float v = raw[(size_t)row * (nheads * 64) + hd * 64 + lane];
  float ss = v * v;
#pragma unroll
  for (int d = 1; d < 64; d <<= 1) ss += __shfl_xor(ss, d);
  float inv = 1.0f / fmaxf(sqrtf(ss), 1e-12f);
  v = v * inv * scale[lane];
  float f = (lane < 32) ? freqs[t * 32 + lane] : 0.0f;
  float sn, cs;
  sincosf(f, &sn, &cs);
  float partner = __shfl_xor(v, 1);
  float rot = (lane & 1) ? partner : -partner;
  float vrot = v * cs + rot * sn;
  if (lane < 32) v = vrot;
  v *= final_scale;
  out[(((size_t)b * nheads + hd) * 1024 + t) * 64 + lane] = f2bf(v);
}

// ---------------- V epilogue: rope + store transposed (B,KV,D,T) bf16 ----------------
__global__ void epilogue_v_kernel(const float* __restrict__ v_raw, const float* __restrict__ freqs,
                                  u16* __restrict__ Vt) {
  __shared__ __align__(16) u16 tile[64][72];
  int blk = blockIdx.x;
  int t0 = (blk & 15) * 64;
  int kvg = blk >> 4;            // b*8 + kv
  int kvv = kvg & 7;
  int bb = kvg >> 3;
  int tid = threadIdx.x;
  int tl = tid >> 2;             // token local 0..63
  int dq = (tid & 3) * 16;       // dim base
  int t = t0 + tl;
  const float* src = v_raw + ((size_t)(bb * 1024 + t)) * 512 + kvv * 64 + dq;
  float x[16];
#pragma unroll
  for (int i = 0; i < 4; ++i) {
    float4 q = *(const float4*)(src + i * 4);
    x[i * 4 + 0] = q.x; x[i * 4 + 1] = q.y; x[i * 4 + 2] = q.z; x[i * 4 + 3] = q.w;
  }
  if (dq < 32) {
#pragma unroll
    for (int j = 0; j < 8; ++j) {
      int d = dq + 2 * j;
      float f = freqs[t * 32 + d];
      float sn, cs; sincosf(f, &sn, &cs);
      float e = x[2 * j], o = x[2 * j + 1];
      x[2 * j]     = e * cs - o * sn;
      x[2 * j + 1] = o * cs + e * sn;
    }
  }
#pragma unroll
  for (int i = 0; i < 16; ++i) tile[dq + i][tl] = f2bf(x[i]);
  __syncthreads();
#pragma unroll
  for (int rnd = 0; rnd < 2; ++rnd) {
    int chunk = rnd * 256 + tid;
    int drow = chunk >> 3, c8 = chunk & 7;
    bf16x8 val = *(const bf16x8*)((const char*)&tile[0][0] + drow * 144 + c8 * 16);
    *(bf16x8*)(Vt + ((size_t)kvg * 64 + drow) * 1024 + t0 + c8 * 8) = val;
  }
}

// ---------------- flash attention: 4-wave intra-block split-K, swapped 32x32 MFMA ----------------
// Wave w handles 32-key steps {w, w+4, ...}; barrier-free K-loop; LDS merge at end.
// S^T = K·Q^T -> lane (q=lane&31, hi=lane>>5) holds S[key=crow(r,hi)][q], crow=(r&3)+8*(r>>2)+4*hi
// O^T = V^T·P^T -> same lane holds O[d=32*dh+crow(r,hi)][q]
// Register discipline (round-5 lesson): NO K prefetch (K is L2-hot, TLP hides it);
// bias IS prefetched (L3 stream, long latency). launch_bounds(256,3) -> cap 170, no spill.
__device__ __forceinline__ unsigned pack_bf2(float lo, float hi_) {
  union { __bf16 h[2]; unsigned u; } c;
  c.h[0] = (__bf16)lo; c.h[1] = (__bf16)hi_;
  return c.u;
}

__global__ __launch_bounds__(256, 3) void attn_kernel(const u16* __restrict__ Qb, const u16* __restrict__ Kb,
                                                      const u16* __restrict__ Vtb, const float* __restrict__ bias,
                                                      u16* __restrict__ Yb) {
  __shared__ __align__(16) float Osh[4][64][32];   // 32 KB f32 partial O^T per wave
  __shared__ float Msh[4][32];
  __shared__ float Lsh[4][32];
  int tid = threadIdx.x;
  int w = tid >> 6;              // wave index = key-split slot
  int lane = tid & 63;
  int ql = lane & 31;            // this lane's query column
  int hi = lane >> 5;
  int x = blockIdx.x;
  int qt = 31 - (x >> 6);        // qt descending: long blocks dispatch first
  int bh = x & 63;               // h*4 + b : b fastest => 4 batches share bias panel in L2
  int b = bh & 3, h = bh >> 2, kv = h & 7;
  int qg = qt * 32 + ql;         // global query row
  int nt = qt + 1;               // total 32-key steps (causal)

  // Q fragments (B-operand): col=ql, per-lane 8 dims at hi*8 within each 16-dim k-slice
  const u16* Qrow = Qb + ((size_t)(b * 16 + h) * 1024 + qg) * 64;
  bf16x8 qf[4];
#pragma unroll
  for (int ks = 0; ks < 4; ++ks) qf[ks] = *(const bf16x8*)(Qrow + ks * 16 + hi * 8);

  const u16* Kfp = Kb + (size_t)(b * 8 + kv) * 1024 * 64 + (size_t)ql * 64 + hi * 8;
  const u16* Vfp = Vtb + (size_t)(b * 8 + kv) * 64 * 1024 + (size_t)ql * 1024 + hi * 8;
  const float* biasrow = bias + (size_t)h * 1024 * 1024 + (size_t)qg * 1024;

  f32x16 o0, o1;
#pragma unroll
  for (int r = 0; r < 16; ++r) { o0[r] = 0.f; o1[r] = 0.f; }
  float m = -1e30f, lsum = 0.f;

  // prologue: prefetch this wave's first-step bias (long-latency L3 stream)
  float bcf[16];
  {
    int t0 = w * 32;
#pragma unroll
    for (int c = 0; c < 4; ++c) {
      float4 t = *(const float4*)(biasrow + t0 + 8 * c + 4 * hi);
      bcf[c * 4 + 0] = t.x; bcf[c * 4 + 1] = t.y; bcf[c * 4 + 2] = t.z; bcf[c * 4 + 3] = t.w;
    }
  }

  for (int it = w; it < nt; it += 4) {
    int t0 = it * 32;
    bool hn = (it + 4) < nt;
    // ---- issue all loads for this step up-front ----
    bf16x8 kc[4];
#pragma unroll
    for (int ks = 0; ks < 4; ++ks) kc[ks] = *(const bf16x8*)(Kfp + (size_t)t0 * 64 + ks * 16);
    bf16x8 vf[2][2];
#pragma unroll
    for (int dh = 0; dh < 2; ++dh)
#pragma unroll
      for (int k2 = 0; k2 < 2; ++k2)
        vf[dh][k2] = *(const bf16x8*)(Vfp + (size_t)dh * 32 * 1024 + t0 + k2 * 16);
    float bnf[16];
    if (hn) {
#pragma unroll
      for (int c = 0; c < 4; ++c) {
        float4 t = *(const float4*)(biasrow + t0 + 128 + 8 * c + 4 * hi);
        bnf[c * 4 + 0] = t.x; bnf[c * 4 + 1] = t.y; bnf[c * 4 + 2] = t.z; bnf[c * 4 + 3] = t.w;
      }
    }
    // ---- S^T = K · Q^T (scales + log2e folded into Q; bias pre-scaled by log2e at launch) ----
    f32x16 s;
#pragma unroll
    for (int r = 0; r < 16; ++r) s[r] = 0.f;
#pragma unroll
    for (int ks = 0; ks < 4; ++ks)
      s = __builtin_amdgcn_mfma_f32_32x32x16_bf16(kc[ks], qf[ks], s, 0, 0, 0);
    // ---- bias + causal mask ----
    bool diag = (it == nt - 1);
    float p[16];
#pragma unroll
    for (int r = 0; r < 16; ++r) {
      int key = t0 + (r & 3) + 8 * (r >> 2) + 4 * hi;
      float sv = s[r] + bcf[r];
      if (diag && key > qg) sv = -1e30f;
      p[r] = sv;
    }
    // ---- row max: in-register tree + one xor-32 exchange ----
    float t8[8];
#pragma unroll
    for (int j = 0; j < 8; ++j) t8[j] = fmaxf(p[2 * j], p[2 * j + 1]);
    float t4a = fmaxf(t8[0], t8[1]), t4b = fmaxf(t8[2], t8[3]);
    float t4c = fmaxf(t8[4], t8[5]), t4d = fmaxf(t8[6], t8[7]);
    float mx = fmaxf(fmaxf(t4a, t4b), fmaxf(t4c, t4d));
    mx = fmaxf(mx, __shfl_xor(mx, 32));
    // ---- defer-max (THR=8 in log2 units) ----
    if (!__all(mx <= m + 8.0f)) {
      float mn = fmaxf(m, mx);
      float sf = exp2f(m - mn);
      m = mn;
      lsum *= sf;
#pragma unroll
      for (int r = 0; r < 16; ++r) { o0[r] *= sf; o1[r] *= sf; }
    }
    // ---- exponentiate (bounded by 2^8) + lane-partial sum ----
    float ssum = 0.f;
#pragma unroll
    for (int r = 0; r < 16; ++r) {
      p[r] = exp2f(p[r] - m);
      ssum += p[r];
    }
    lsum += ssum;
    // ---- pack P -> bf16 pairs, redistribute across the hi-split (8 xor-32 shuffles) ----
    unsigned pk[8], tk[8];
#pragma unroll
    for (int j = 0; j < 8; ++j) pk[j] = pack_bf2(p[2 * j], p[2 * j + 1]);
#pragma unroll
    for (int j = 0; j < 8; ++j) tk[j] = (unsigned)__shfl_xor((int)pk[j], 32);
    union PU { unsigned u[4]; bf16x8 v; };
    PU pb0, pb1;
    pb0.u[0] = hi ? tk[2] : pk[0];
    pb0.u[1] = hi ? tk[3] : pk[1];
    pb0.u[2] = hi ? pk[2] : tk[0];
    pb0.u[3] = hi ? pk[3] : tk[1];
    pb1.u[0] = hi ? tk[6] : pk[4];
    pb1.u[1] = hi ? tk[7] : pk[5];
    pb1.u[2] = hi ? pk[6] : tk[4];
    pb1.u[3] = hi ? pk[7] : tk[5];
    // ---- O^T += V^T · P^T ----
    o0 = __builtin_amdgcn_mfma_f32_32x32x16_bf16(vf[0][0], pb0.v, o0, 0, 0, 0);
    o0 = __builtin_amdgcn_mfma_f32_32x32x16_bf16(vf[0][1], pb1.v, o0, 0, 0, 0);
    o1 = __builtin_amdgcn_mfma_f32_32x32x16_bf16(vf[1][0], pb0.v, o1, 0, 0, 0);
    o1 = __builtin_amdgcn_mfma_f32_32x32x16_bf16(vf[1][1], pb1.v, o1, 0, 0, 0);
    // roll bias prefetch
    if (hn) {
#pragma unroll
      for (int r = 0; r < 16; ++r) bcf[r] = bnf[r];
    }
  }

  // ---- write this wave's partial state to LDS ----
  lsum += __shfl_xor(lsum, 32);
#pragma unroll
  for (int r = 0; r < 16; ++r) {
    int row = (r & 3) + 8 * (r >> 2) + 4 * hi;
    Osh[w][row][ql]      = o0[r];
    Osh[w][row + 32][ql] = o1[r];
  }
  if (hi == 0) { Msh[w][ql] = m; Lsh[w][ql] = lsum; }
  __syncthreads();

  // ---- merge 4 partials: thread handles (q = tid&31, d = (tid>>5)*8 .. +7) ----
  {
    int q = tid & 31, dg = tid >> 5;
    float m0 = Msh[0][q], m1 = Msh[1][q], m2 = Msh[2][q], m3 = Msh[3][q];
    float mM = fmaxf(fmaxf(m0, m1), fmaxf(m2, m3));
    float w0 = exp2f(m0 - mM), w1 = exp2f(m1 - mM);
    float w2 = exp2f(m2 - mM), w3 = exp2f(m3 - mM);
    float ltot = w0 * Lsh[0][q] + w1 * Lsh[1][q] + w2 * Lsh[2][q] + w3 * Lsh[3][q];
    float invl = 1.0f / ltot;
    ushort4 out0, out1;
    u16 ov[8];
#pragma unroll
    for (int j = 0; j < 8; ++j) {
      int d = dg * 8 + j;
      float acc = w0 * Osh[0][d][q] + w1 * Osh[1][d][q] + w2 * Osh[2][d][q] + w3 * Osh[3][d][q];
      ov[j] = f2bf(acc * invl);
    }
    out0.x = ov[0]; out0.y = ov[1]; out0.z = ov[2]; out0.w = ov[3];
    out1.x = ov[4]; out1.y = ov[5]; out1.z = ov[6]; out1.w = ov[7];
    u16* Yp = Yb + ((size_t)b * 1024 + qt * 32 + q) * 1024 + h * 64 + dg * 8;
    *(ushort4*)Yp = out0;
    *(ushort4*)(Yp + 4) = out1;
  }
}

extern "C" void kernel_launch(void* const* d_in, const int* in_sizes, int n_in,
                              void* d_out, int out_size, void* d_ws, size_t ws_size,
                              hipStream_t stream) {
  const float* x     = (const float*)d_in[0];
  const float* enc   = (const float*)d_in[1];
  const float* freqs = (const float*)d_in[2];
  const float* bias  = (const float*)d_in[3];
  const float* Wq    = (const float*)d_in[4];
  const float* Wk    = (const float*)d_in[5];
  const float* Wv    = (const float*)d_in[6];
  const float* Wo    = (const float*)d_in[7];
  const float* qs    = (const float*)d_in[8];
  const float* ks    = (const float*)d_in[9];

  char* ws = (char*)d_ws;
  size_t off = 0;
  auto alloc = [&](size_t bytes) { char* p = ws + off; off += (bytes + 255) & ~(size_t)255; return p; };
  u16*   xb  = (u16*)alloc(8388608);    // x bf16 (4096 x 1024)
  u16*   eb  = (u16*)alloc(8388608);    // enc bf16
  u16*   WqT = (u16*)alloc(2097152);    // (1024 x 1024)
  u16*   WkT = (u16*)alloc(1048576);    // (512 x 1024)
  u16*   WvT = (u16*)alloc(1048576);
  u16*   WoT = (u16*)alloc(2097152);
  float* qr  = (float*)alloc(16777216); // q raw f32 (4096 x 1024)
  float* kr  = (float*)alloc(8388608);  // k raw (4096 x 512)
  float* vr  = (float*)alloc(8388608);
  u16*   Qb  = (u16*)alloc(8388608);    // (B,H,T,D) bf16
  u16*   Kbb = (u16*)alloc(4194304);    // (B,KV,T,D)
  u16*   Vtb = (u16*)alloc(4194304);    // (B,KV,D,T)
  u16*   Yb  = (u16*)xb;                // alias: xb dead after QKV GEMM

  cast2_kernel<<<2048, 256, 0, stream>>>(x, enc, xb, eb, 1048576);
  transpose_cast4_kernel<<<dim3(32, 32, 4), dim3(32, 8), 0, stream>>>(Wq, Wk, Wv, Wo, WqT, WkT, WvT, WoT);

  gemm_qkv_kernel<<<dim3(32, 8, 3), 256, 0, stream>>>(xb, eb, WqT, WkT, WvT, qr, kr, vr);

  epilogue_qk2_kernel<<<24576, 256, 0, stream>>>(qr, kr, qs, ks, freqs, Qb, Kbb);
  epilogue_v_kernel<<<512, 256, 0, stream>>>(vr, freqs, Vtb);

  attn_kernel<<<dim3(2048), 256, 0, stream>>>(Qb, Kbb, Vtb, bias, Yb);

  gemm_out_kernel<<<dim3(32, 8), 256, 0, stream>>>(Yb, WoT, (float*)d_out);
}